// Round 7
// baseline (237.485 us; speedup 1.0000x reference)
//
#include <hip/hip_runtime.h>

// SSIM (window=8 box sums) over 96 images of 512x512 fp32.
// v7: barrier-free wave-autonomous, built from measured-good parts only:
//  - one 64-lane wave per (image, 16-row strip); lane owns cols c0=lane*4 and
//    256+c0 (two segments -> every global/LDS op is b128 with 16 B lane
//    stride, the pattern that measured 0 bank conflicts in v1/v3/v5)
//  - raw-pixel register ring (32 float4), literal-indexed via unrolled macro
//  - horizontal 8-sum: per-wave LDS publish + wave_barrier/sched_barrier
//    fences (single wave => no s_barrier => vmcnt NEVER force-drained);
//    own float4 from REGISTER, only +4/+8 from LDS (v6's own-from-LDS read
//    triple caused 4.65M conflicts); row-parity double buffer kills the
//    cross-lane WAR between row r's reads and row r+1's writes
//  - 2-deep prefetch, consume-then-issue: ~2 row-times (~1300 cyc) flight
//  - __launch_bounds__(64,1): VGPR cap 512 (v4 lesson: (64,2) made the
//    allocator clamp to 128 and spill 47 MB; footprint here ~230)

#define W 512
#define OW 505
#define OH 505
#define TH 16
#define NSTRIP ((OH + TH - 1) / TH)   // 32
#define NIMG 96
#define NPIX (96.0 * 505.0 * 505.0)   // 24482400

__device__ __forceinline__ float4 ld4(const float* p) { return *(const float4*)p; }
__device__ __forceinline__ float4 f4add(float4 a, float4 b) {
    return make_float4(a.x + b.x, a.y + b.y, a.z + b.z, a.w + b.w);
}
__device__ __forceinline__ float4 f4sub(float4 a, float4 b) {
    return make_float4(a.x - b.x, a.y - b.y, a.z - b.z, a.w - b.w);
}
__device__ __forceinline__ float4 f4mul(float4 a, float4 b) {
    return make_float4(a.x * b.x, a.y * b.y, a.z * b.z, a.w * b.w);
}

#define FENCE do { __builtin_amdgcn_sched_barrier(0);                      \
                   __builtin_amdgcn_wave_barrier();                        \
                   __builtin_amdgcn_sched_barrier(0); } while (0)

__global__ void finalize(const double* p, float* out) {
    out[0] = 1.0f - (float)(*p / NPIX);
}

__global__ void __launch_bounds__(64, 1)
ssim_main(const float* __restrict__ gt, const float* __restrict__ ni,
          double* __restrict__ acc_out)
{
    const int lane = threadIdx.x;         // 0..63
    const int cA   = lane * 4;            // segment A cols cA..cA+3   (0..255)
    const int cB   = 256 + cA;            // segment B cols cB..cB+3 (256..511)
    const int img  = blockIdx.y;
    const int R0   = blockIdx.x * TH;     // first output row (mult of 16)
    const int R1   = min(R0 + TH, OH);

    const float C1 = 1e-4f, C2 = 9e-4f;

    const float* gx = gt + (size_t)img * (W * W);
    const float* gy = ni + (size_t)img * (W * W);

    // per-wave exchange buffer, row-parity double buffered:
    // [parity][quantity][column]; width 520 so lane 63's segment-B reads at
    // cols 512..519 are in-bounds (garbage, predicated out).
    __shared__ float vbuf[2][4][520];

    // raw-pixel register ring (literal-indexed only)
    float4 rxA[8], rxB[8], ryA[8], ryB[8];

    float4 vsxA = make_float4(0,0,0,0), vsxB = make_float4(0,0,0,0); // sum x
    float4 vsyA = make_float4(0,0,0,0), vsyB = make_float4(0,0,0,0); // sum y
    float4 vsqA = make_float4(0,0,0,0), vsqB = make_float4(0,0,0,0); // sum x^2+y^2
    float4 vspA = make_float4(0,0,0,0), vspB = make_float4(0,0,0,0); // sum x*y

    // warm-up: rows R0..R0+6 -> ring slots 0..6; slot 7 = zeros
#pragma unroll
    for (int k = 0; k < 7; ++k) {
        const float* bx = gx + (size_t)(R0 + k) * W;
        const float* by = gy + (size_t)(R0 + k) * W;
        float4 xA = ld4(bx + cA), xB = ld4(bx + cB);
        float4 yA = ld4(by + cA), yB = ld4(by + cB);
        rxA[k] = xA; rxB[k] = xB; ryA[k] = yA; ryB[k] = yB;
        vsxA = f4add(vsxA, xA); vsxB = f4add(vsxB, xB);
        vsyA = f4add(vsyA, yA); vsyB = f4add(vsyB, yB);
        vsqA = f4add(vsqA, f4add(f4mul(xA,xA), f4mul(yA,yA)));
        vsqB = f4add(vsqB, f4add(f4mul(xB,xB), f4mul(yB,yB)));
        vspA = f4add(vspA, f4mul(xA,yA));
        vspB = f4add(vspB, f4mul(xB,yB));
    }
    rxA[7] = rxB[7] = ryA[7] = ryB[7] = make_float4(0,0,0,0);

    // 2-deep prefetch: slot0 <- row R0+7, slot1 <- row R0+8 (R0+8 <= 504)
    float4 pfxA[2], pfxB[2], pfyA[2], pfyB[2];
    {
        const float* bx = gx + (size_t)(R0 + 7) * W;
        const float* by = gy + (size_t)(R0 + 7) * W;
        pfxA[0] = ld4(bx + cA); pfxB[0] = ld4(bx + cB);
        pfyA[0] = ld4(by + cA); pfyB[0] = ld4(by + cB);
    }
    {
        const float* bx = gx + (size_t)(R0 + 8) * W;
        const float* by = gy + (size_t)(R0 + 8) * W;
        pfxA[1] = ld4(bx + cA); pfxB[1] = ld4(bx + cB);
        pfyA[1] = ld4(by + cA); pfyB[1] = ld4(by + cB);
    }

    float acc = 0.0f;

// horizontal 8-window sliding sums: own float4 from REGISTER, +4/+8 from LDS
#define HORIZ(q, v, base, Bq) {                                           \
        float4 n1 = *(float4*)&vbuf[b][q][(base) + 4];                    \
        float4 n2 = *(float4*)&vbuf[b][q][(base) + 8];                    \
        float s = ((v.x + v.y) + (v.z + v.w)) +                           \
                  ((n1.x + n1.y) + (n1.z + n1.w));                        \
        Bq[0] = s;                                                        \
        s += n2.x - v.x; Bq[1] = s;                                       \
        s += n2.y - v.y; Bq[2] = s;                                       \
        s += n2.z - v.z; Bq[3] = s;                                       \
    }

#define SSIM4(Bm, colbase, CHECK) {                                       \
        _Pragma("unroll")                                                 \
        for (int j = 0; j < 4; ++j) {                                     \
            float Sx = Bm[0][j], Sy = Bm[1][j];                           \
            float Sq = Bm[2][j], Sp = Bm[3][j];                           \
            float mu12 = Sx * Sy;                                         \
            float n1v = 2.0f * mu12 + C1;                                 \
            float n2v = 2.0f * (Sp - mu12) + C2;                          \
            float sx2 = Sx * Sx, sy2 = Sy * Sy;                           \
            float d1  = sx2 + sy2 + C1;                                   \
            float d2  = (Sq - sx2 - sy2) + C2;                            \
            float sv  = (n1v * n2v) * __builtin_amdgcn_rcpf(d1 * d2);     \
            if (!(CHECK) || ((colbase) + j < OW)) acc += sv;              \
        }                                                                 \
    }

#define ROWBODY(k, slot) {                                                \
        const int r = rbase + (k);                                        \
        if (r < R1) { /* wave-uniform */                                  \
            const int b = (k) & 1;                                        \
            float4 cxA = pfxA[b], cxB = pfxB[b];  /* vmcnt wait here */   \
            float4 cyA = pfyA[b], cyB = pfyB[b];                          \
            if (r + 2 < R1) { /* row r+9 <= 511, consumed at iter r+2 */  \
                const float* bx = gx + (size_t)(r + 9) * W;               \
                const float* by = gy + (size_t)(r + 9) * W;               \
                pfxA[b] = ld4(bx + cA); pfxB[b] = ld4(bx + cB);           \
                pfyA[b] = ld4(by + cA); pfyB[b] = ld4(by + cB);           \
            }                                                             \
            { /* vertical slide, segment A */                             \
                float4 ox = rxA[slot], oy = ryA[slot];                    \
                vsxA = f4add(f4sub(vsxA, ox), cxA);                       \
                vsyA = f4add(f4sub(vsyA, oy), cyA);                       \
                vsqA = f4add(vsqA, f4sub(f4add(f4mul(cxA,cxA), f4mul(cyA,cyA)), \
                                         f4add(f4mul(ox,ox),   f4mul(oy,oy)))); \
                vspA = f4add(vspA, f4sub(f4mul(cxA,cyA), f4mul(ox,oy)));  \
                rxA[slot] = cxA; ryA[slot] = cyA;                         \
            }                                                             \
            { /* vertical slide, segment B */                             \
                float4 ox = rxB[slot], oy = ryB[slot];                    \
                vsxB = f4add(f4sub(vsxB, ox), cxB);                       \
                vsyB = f4add(f4sub(vsyB, oy), cyB);                       \
                vsqB = f4add(vsqB, f4sub(f4add(f4mul(cxB,cxB), f4mul(cyB,cyB)), \
                                         f4add(f4mul(ox,ox),   f4mul(oy,oy)))); \
                vspB = f4add(vspB, f4sub(f4mul(cxB,cyB), f4mul(ox,oy)));  \
                rxB[slot] = cxB; ryB[slot] = cyB;                         \
            }                                                             \
            FENCE; /* prior row's LDS reads stay below next writes */     \
            *(float4*)&vbuf[b][0][cA] = vsxA;                             \
            *(float4*)&vbuf[b][0][cB] = vsxB;                             \
            *(float4*)&vbuf[b][1][cA] = vsyA;                             \
            *(float4*)&vbuf[b][1][cB] = vsyB;                             \
            *(float4*)&vbuf[b][2][cA] = vsqA;                             \
            *(float4*)&vbuf[b][2][cB] = vsqB;                             \
            *(float4*)&vbuf[b][3][cA] = vspA;                             \
            *(float4*)&vbuf[b][3][cB] = vspB;                             \
            FENCE; /* writes complete (in-order DS pipe) before reads */  \
            { /* segment A: cols cA..cA+3 <= 255 < OW, no predicate */    \
                float B4[4][4];                                           \
                HORIZ(0, vsxA, cA, B4[0]) HORIZ(1, vsyA, cA, B4[1])       \
                HORIZ(2, vsqA, cA, B4[2]) HORIZ(3, vspA, cA, B4[3])       \
                SSIM4(B4, cA, 0)                                          \
            }                                                             \
            { /* segment B: cols cB..cB+3, predicate lanes 62/63 */       \
                float B4[4][4];                                           \
                HORIZ(0, vsxB, cB, B4[0]) HORIZ(1, vsyB, cB, B4[1])       \
                HORIZ(2, vsqB, cB, B4[2]) HORIZ(3, vspB, cB, B4[3])       \
                SSIM4(B4, cB, 1)                                          \
            }                                                             \
        }                                                                 \
    }

    // R0 mult of 16 -> rbase even; ring slot (r-R0+7)&7 = (k+7)&7 literal
    for (int rbase = R0; rbase < R1; rbase += 8) {
        ROWBODY(0, 7)
        ROWBODY(1, 0)
        ROWBODY(2, 1)
        ROWBODY(3, 2)
        ROWBODY(4, 3)
        ROWBODY(5, 4)
        ROWBODY(6, 5)
        ROWBODY(7, 6)
    }

    // wave reduction -> one double atomic per wave
#pragma unroll
    for (int off = 32; off; off >>= 1) acc += __shfl_down(acc, off);
    if (lane == 0) atomicAdd(acc_out, (double)acc);
}

extern "C" void kernel_launch(void* const* d_in, const int* in_sizes, int n_in,
                              void* d_out, int out_size, void* d_ws, size_t ws_size,
                              hipStream_t stream) {
    const float* gt = (const float*)d_in[0];
    const float* ni = (const float*)d_in[1];
    double* acc = (double*)d_ws;   // 8 bytes scratch, re-poisoned every call

    hipMemsetAsync(acc, 0, sizeof(double), stream);
    dim3 grid(NSTRIP, NIMG);
    ssim_main<<<grid, 64, 0, stream>>>(gt, ni, acc);
    finalize<<<1, 1, 0, stream>>>(acc, (float*)d_out);
}